// Round 9
// baseline (479.541 us; speedup 1.0000x reference)
//
#include <hip/hip_runtime.h>

// RuleFilter: out[0] = logits[0]; out[i] = logits[i] * mask_table[argmax(out[i-1])]
// logits: (L=128, N=4096, V=128) fp32, mask_table: (V,V) fp32 {0,1}.
//
// R9: producer/consumer wave specialization. Measured model from R0-R8:
//   step_time = max(bytes_per_wave_step / 0.86 GB/s, chain_latency)
// R4 (1 wave/seq) is exactly at this limit (1KB/step -> 1.19us -> 152us).
// R8's lockstep vocab-split paid a ~0.7us/step barrier+jitter tax.
// Here each 128-thread block = 1 sequence, 2 DECOUPLED waves:
//   wave0 PRODUCER: loads rows (512B/step, read-only ring), runs the argmax
//     chain, publishes prev for row i+1 as one u32 (0x100|p) in LDS.
//     Fire-and-forget (128-entry queue) -> never waits on consumer.
//   wave1 CONSUMER: prefetches the same rows independently (loads don't
//     depend on prev), spins on the flag (normally ready), masks, stores.
// 512B/wave-step -> 0.6us at the per-wave BW cap; 8192 waves = 32/CU.
// No barrier in the chain; handoff = single-word volatile LDS write/read.
// VGPR <= 64 enforced via __launch_bounds__(128, 8).

constexpr int V = 128;
constexpr int L = 128;
constexpr int N = 4096;
constexpr int D  = 15;   // rows in flight
constexpr int RD = 16;   // ring slots
constexpr unsigned ROWB = (unsigned)N * V * 4;  // 2 MiB between rows

typedef __attribute__((ext_vector_type(2))) float f32x2;
typedef unsigned long long u64;

// Full 64-lane max, broadcast (HW-verified R0-R8).
__device__ __forceinline__ float wave_max_dpp(float x) {
    int v = __float_as_int(x);
    const int ninf = __float_as_int(-__builtin_inff());
#define RF_STEP(ctrl)                                                          \
    {                                                                          \
        int s = __builtin_amdgcn_update_dpp(ninf, v, ctrl, 0xf, 0xf, false);   \
        v = __float_as_int(fmaxf(__int_as_float(v), __int_as_float(s)));       \
    }
    RF_STEP(0x111) RF_STEP(0x112) RF_STEP(0x114) RF_STEP(0x118)
    RF_STEP(0x142) RF_STEP(0x143)
#undef RF_STEP
    return __int_as_float(__builtin_amdgcn_readlane(v, 63));
}

// argmax over {f.x@2*lane, f.y@2*lane+1}; ties -> lowest index (HW-verified).
__device__ __forceinline__ int wave_argmax(f32x2 f) {
    const float bv = wave_max_dpp(fmaxf(f.x, f.y));
    u64 b0 = __ballot(f.x == bv);
    u64 b1 = __ballot(f.y == bv);
    int i0 = __ffsll(b0), i1 = __ffsll(b1);
    int c0 = i0 ? (i0 - 1) * 2 : (1 << 30);
    int c1 = i1 ? (i1 - 1) * 2 + 1 : (1 << 30);
    return min(c0, c1);
}

__device__ __forceinline__ unsigned sel8(const unsigned* t, int j) {
    unsigned a0 = (j & 1) ? t[1] : t[0];
    unsigned a1 = (j & 1) ? t[3] : t[2];
    unsigned a2 = (j & 1) ? t[5] : t[4];
    unsigned a3 = (j & 1) ? t[7] : t[6];
    unsigned b0 = (j & 2) ? a1 : a0;
    unsigned b1 = (j & 2) ? a3 : a2;
    return (j & 4) ? b1 : b0;
}

__device__ __forceinline__ u64 uniform_u64(const void* p) {
    u64 x = (u64)p;
    unsigned lo = __builtin_amdgcn_readfirstlane((unsigned)x);
    unsigned hi = __builtin_amdgcn_readfirstlane((unsigned)(x >> 32));
    return ((u64)hi << 32) | lo;
}

// One step at ring phase J; absolute row I = irow + J.
// PROD: producer role. PH: 0=prologue,1=steady,2=epilogue.
// vmcnt ledgers (exact, derived from issue order; never 0 mid-stream):
//   producer (1 load/step, no stores): NW = 15 everywhere except epi J>0: 15-J.
//   consumer (1 load + 1 store/step):  pro: 15+J; steady: 30; epi J>0: 30-J.
template <bool PROD, int PH, int J>
struct Walk {
    static constexpr int  NW    = PROD ? ((PH == 2 && J > 0) ? (15 - J) : 15)
                                       : ((PH == 0) ? (15 + J)
                                          : ((PH == 2 && J > 0) ? (30 - J) : 30));
    static constexpr bool PF    = (PH != 2) || (J == 0);
    static constexpr bool FIRST = (PH == 0 && J == 0);
    static constexpr bool LAST  = (PH == 2 && J == 15);
    static constexpr int  rs    = J & 15;
    static constexpr int  ps    = (J + D) & 15;  // slot consumed last step

    static __device__ __forceinline__ void run(f32x2* ring, const unsigned* tbl,
                                               int& prev, int irow, unsigned ibase,
                                               u64 lbase, u64 obase,
                                               volatile unsigned* flg, int lane) {
        if constexpr (PF) {
            unsigned voff = ibase + (unsigned)(J + D) * ROWB;
            asm volatile("global_load_dwordx2 %0, %1, %2"
                         : "=&v"(ring[ps])
                         : "v"(voff), "s"(lbase));
        }

        // Retires load of row I (consumer: also the 16-old store -> WAR safe).
        asm volatile("s_waitcnt vmcnt(%c1)" : "+v"(ring[rs]) : "i"(NW));

        f32x2 c = ring[rs];

        if constexpr (PROD) {
            f32x2 f;
            if constexpr (FIRST) {
                f = c;  // row 0 unfiltered
            } else {
                unsigned word = sel8(tbl, prev >> 4);
                unsigned fb   = (word >> ((prev & 15) * 2)) & 3u;
                f.x = (fb & 1u) ? c.x : 0.0f;
                f.y = (fb & 2u) ? c.y : 0.0f;
            }
            if constexpr (!LAST) {
                prev = wave_argmax(f);
                if (lane == 0) flg[irow + J + 1] = 0x100u | (unsigned)prev;
            }
        } else {
            f32x2 f;
            if constexpr (FIRST) {
                f = c;  // row 0 unfiltered
            } else {
                unsigned v;
                while ((v = flg[irow + J]) == 0u) {}  // normally already set
                int pv = (int)(v & 127u);
                unsigned word = sel8(tbl, pv >> 4);
                unsigned fb   = (word >> ((pv & 15) * 2)) & 3u;
                f.x = (fb & 1u) ? c.x : 0.0f;
                f.y = (fb & 2u) ? c.y : 0.0f;
            }
            ring[rs] = f;  // in-place store-data (ledger proves WAR-safe)
            unsigned voff = ibase + (unsigned)J * ROWB;
            asm volatile("global_store_dwordx2 %0, %1, %2"
                         :: "v"(voff), "v"(ring[rs]), "s"(obase));
        }

        Walk<PROD, PH, J + 1>::run(ring, tbl, prev, irow, ibase, lbase, obase,
                                   flg, lane);
    }
};
template <bool PROD, int PH>
struct Walk<PROD, PH, 16> {
    static __device__ __forceinline__ void run(f32x2*, const unsigned*, int&,
                                               int, unsigned, u64, u64,
                                               volatile unsigned*, int) {}
};

template <bool PROD>
__device__ __forceinline__ void walk_all(f32x2* ring, const unsigned* tbl,
                                         u64 lbase, u64 obase,
                                         volatile unsigned* flg,
                                         int lane, unsigned laneoff) {
    int prev = 0;
    int irow = 0;
    unsigned ibase = laneoff;
    Walk<PROD, 0, 0>::run(ring, tbl, prev, irow, ibase, lbase, obase, flg, lane);
    irow = 16; ibase += 16u * ROWB;
#pragma unroll 1
    for (int m = 0; m < 6; ++m) {
        Walk<PROD, 1, 0>::run(ring, tbl, prev, irow, ibase, lbase, obase, flg, lane);
        irow += 16; ibase += 16u * ROWB;
    }
    Walk<PROD, 2, 0>::run(ring, tbl, prev, irow, ibase, lbase, obase, flg, lane);
}

__global__ __launch_bounds__(128, 8) void rule_filter_kernel(
    const float* __restrict__ logits,      // (L, N, V)
    const float* __restrict__ mask_table,  // (V, V)
    float* __restrict__ out)               // (L, N, V)
{
    __shared__ unsigned flgs[132];  // [i] = 0 until ready, then 0x100|prev(i)

    const int h    = threadIdx.x >> 6;  // 0 = producer, 1 = consumer
    const int lane = threadIdx.x & 63;
    const int n    = blockIdx.x;        // sequence

    const u64 lbase = uniform_u64(logits + (size_t)n * V);
    const u64 obase = uniform_u64(out    + (size_t)n * V);
    const unsigned laneoff = (unsigned)lane * 8;  // dwordx2 per lane

    // Per-lane mask table: tbl[j] bits(2r..2r+1) = mask_table[16j+r][2l..2l+1]
    unsigned tbl[8];
#pragma unroll 1
    for (int j = 0; j < 8; ++j) {
        unsigned acc = 0;
#pragma unroll
        for (int r = 0; r < 16; ++r) {
            const int p = j * 16 + r;
            float2 mv = *(const float2*)(mask_table + (size_t)p * V + lane * 2);
            acc |= ((mv.x != 0.0f ? 1u : 0u) | (mv.y != 0.0f ? 2u : 0u)) << (2 * r);
        }
        tbl[j] = acc;
    }

    flgs[threadIdx.x] = 0;
    if (threadIdx.x < 4) flgs[128 + threadIdx.x] = 0;
    __syncthreads();  // drains vmcnt+lgkmcnt -> exact ledger baseline
    asm volatile("s_waitcnt vmcnt(0)" ::: "memory");

    f32x2 ring[RD];
    // Prologue: rows 0..14 -> ring[0..14] (vmcnt ops 1..15, in order).
#pragma unroll
    for (int r = 0; r < D; ++r) {
        unsigned voff = (unsigned)r * ROWB + laneoff;
        asm volatile("global_load_dwordx2 %0, %1, %2"
                     : "=&v"(ring[r])
                     : "v"(voff), "s"(lbase));
    }

    volatile unsigned* flg = flgs;
    if (h == 0) walk_all<true >(ring, tbl, lbase, obase, flg, lane, laneoff);
    else        walk_all<false>(ring, tbl, lbase, obase, flg, lane, laneoff);

    // Drain asm stores before return (invisible to the compiler).
    asm volatile("s_waitcnt vmcnt(0)" ::: "memory");
}

extern "C" void kernel_launch(void* const* d_in, const int* in_sizes, int n_in,
                              void* d_out, int out_size, void* d_ws, size_t ws_size,
                              hipStream_t stream) {
    const float* logits     = (const float*)d_in[0];  // (L, N, V) fp32
    const float* mask_table = (const float*)d_in[1];  // (V, V) fp32
    float* out              = (float*)d_out;          // (L, N, V) fp32

    dim3 grid(N);      // one block (producer+consumer wave) per sequence
    dim3 block(128);
    rule_filter_kernel<<<grid, block, 0, stream>>>(logits, mask_table, out);
}